// Round 9
// baseline (22393.054 us; speedup 1.0000x reference)
//
#include <hip/hip_runtime.h>
#include <hip/hip_fp16.h>

#define T_STEPS 4096
#define RES     4096
#define NIN     64
#define NOUT    32
#define NWG     256
#define TPB     512   // 8 waves; wave wv owns cols [512wv,512wv+512) of all 16 rows

typedef unsigned long long ull;
typedef _Float16 half8 __attribute__((ext_vector_type(8)));
typedef float    f32x4 __attribute__((ext_vector_type(4)));

// all 4 encoded halfs nonzero? (published x+2 in (1,3): never 0x0000)
__device__ __forceinline__ bool ok4(ull q) {
    return ((unsigned short)q) && ((unsigned short)(q >> 16)) &&
           ((unsigned short)(q >> 32)) && ((unsigned short)(q >> 48));
}

__global__ void esn_init(unsigned short* __restrict__ Xh) {
    int i = blockIdx.x * 256 + threadIdx.x;
    if (i < RES) Xh[i] = 0x4000;               // half(2.0) == encoded x[0] = 0
}

// ---------------------------------------------------------------------------
// Persistent recurrence, MFMA edition. 256 WGs x 512 thr; WG g owns rows
// 16g..16g+15.  ROUND-8 POST-MORTEM: W-from-LDS costs ~34 ds_read_b128 per
// wave per step -> LDS pipe serializes at ~1.4 us/step. Fix: W lives in
// REGISTERS as MFMA A-fragments (16 x f16x8 = 64 VGPR/lane -- small enough
// that the allocator has no reason to spill, unlike rounds 2-5's 128-256).
// Per wave/step: 16 v_mfma_f32_16x16x32_f16, B = x-slice duplicated across
// cols (only C col 0 is read; C layout HW-verified: col=lane&15,
// row=4*(lane>>4)+reg). Lane<->k layout of A/B is self-consistent by
// construction, so any HW k-permutation cancels in the k-sum.
// Encoding x^=x+2 folded into rs = 2*rowsum(W) (one ones-MFMA at init).
// LDS: only an 8 KB wave-private x bounce + tiny red[]; no barrier before
// compute (wave-local staging), ONE barrier/step for the cross-wave reduce.
// ---------------------------------------------------------------------------
__global__ __launch_bounds__(TPB, 1)
void esn_recur(const float* __restrict__ inp,
               const float* __restrict__ Win,
               const float* __restrict__ W,
               unsigned short* __restrict__ Xh)   // [T][RES] fp16 encoded
{
    __shared__ __align__(16) __half xh[RES];      // 8 KB, wave-private slices
    __shared__ float red[2][16][9];               // padded partials, parity dbuf

    const int g    = blockIdx.x;
    const int tid  = threadIdx.x;
    const int wv   = tid >> 6;
    const int lane = tid & 63;
    const int r    = lane & 15;      // A row within the 16-row tile
    const int q    = lane >> 4;      // k-subgroup 0..3 (8 k's each)

    // ---- A-fragments: W[16g+r][512wv + 32c + 8q + j]  (fp16, 64 VGPRs) ----
    half8 wA[16];
    {
        const float* base = W + (size_t)(g * 16 + r) * RES + wv * 512 + 8 * q;
#pragma unroll
        for (int c = 0; c < 16; ++c) {
            float4 a = *(const float4*)(base + 32 * c);
            float4 b = *(const float4*)(base + 32 * c + 4);
            half8 f;
            f[0] = (_Float16)a.x; f[1] = (_Float16)a.y;
            f[2] = (_Float16)a.z; f[3] = (_Float16)a.w;
            f[4] = (_Float16)b.x; f[5] = (_Float16)b.y;
            f[6] = (_Float16)b.z; f[7] = (_Float16)b.w;
            wA[c] = f;
        }
    }
    // W_in fragments (used by wave 0 only): cols 0..63 as 2 k-chunks
    half8 wI0, wI1;
    if (wv == 0) {
        const float* base = Win + (size_t)(g * 16 + r) * NIN + 8 * q;
#pragma unroll
        for (int cu = 0; cu < 2; ++cu) {
            float4 a = *(const float4*)(base + 32 * cu);
            float4 b = *(const float4*)(base + 32 * cu + 4);
            half8 f;
            f[0] = (_Float16)a.x; f[1] = (_Float16)a.y;
            f[2] = (_Float16)a.z; f[3] = (_Float16)a.w;
            f[4] = (_Float16)b.x; f[5] = (_Float16)b.y;
            f[6] = (_Float16)b.z; f[7] = (_Float16)b.w;
            if (cu == 0) wI0 = f; else wI1 = f;
        }
    }
    // ---- rs = 2 * rowsum(W slice) via ones-MFMA (exact same layout path) --
    f32x4 rs;
    {
        half8 ones;
#pragma unroll
        for (int j = 0; j < 8; ++j) ones[j] = (_Float16)1.0f;
        f32x4 s0 = {0.f, 0.f, 0.f, 0.f}, s1 = {0.f, 0.f, 0.f, 0.f};
#pragma unroll
        for (int c = 0; c < 16; c += 2) {
            s0 = __builtin_amdgcn_mfma_f32_16x16x32_f16(wA[c],     ones, s0, 0, 0, 0);
            s1 = __builtin_amdgcn_mfma_f32_16x16x32_f16(wA[c + 1], ones, s1, 0, 0, 0);
        }
        rs = (s0 + s1) * 2.0f;
    }

    for (int t = 1; t < T_STEPS; ++t) {
        // ---- poll ONLY my wave's 16 B of x[t-1] (data-as-flag) ------------
        const ull* src = (const ull*)(Xh + (size_t)(t - 1) * RES) + 128 * wv + 2 * lane;
        ull q0 = 0, q1 = 0;
        int need = 3;
        do {
            if (need & 1) { q0 = __hip_atomic_load(src,     __ATOMIC_RELAXED, __HIP_MEMORY_SCOPE_AGENT); if (ok4(q0)) need &= ~1; }
            if (need & 2) { q1 = __hip_atomic_load(src + 1, __ATOMIC_RELAXED, __HIP_MEMORY_SCOPE_AGENT); if (ok4(q1)) need &= ~2; }
        } while (need);

        // ---- stage raw encoded slice (wave-private: no barrier needed) ----
        uint4 sv;
        sv.x = (unsigned)q0; sv.y = (unsigned)(q0 >> 32);
        sv.z = (unsigned)q1; sv.w = (unsigned)(q1 >> 32);
        *(uint4*)(xh + 512 * wv + 8 * lane) = sv;
        asm volatile("s_waitcnt lgkmcnt(0)" ::: "memory");

        // ---- 16 MFMAs: acc[c] += A(W) * B(x^ duplicated across cols) ------
        const half8* xb = (const half8*)(xh + 512 * wv + 8 * q);  // +32c = xb[4c]
        f32x4 acc0 = {0.f, 0.f, 0.f, 0.f}, acc1 = {0.f, 0.f, 0.f, 0.f};
#pragma unroll
        for (int c = 0; c < 16; c += 2) {
            acc0 = __builtin_amdgcn_mfma_f32_16x16x32_f16(wA[c],     xb[4 * c],       acc0, 0, 0, 0);
            acc1 = __builtin_amdgcn_mfma_f32_16x16x32_f16(wA[c + 1], xb[4 * (c + 1)], acc1, 0, 0, 0);
        }
        if (wv == 0) {                       // + W_in u_t (u raw, no offset)
            const float* up = inp + (size_t)t * NIN + 8 * q;
            float4 ua = *(const float4*)up,        ub = *(const float4*)(up + 4);
            float4 uc = *(const float4*)(up + 32), ud = *(const float4*)(up + 36);
            half8 b0, b1;
            b0[0] = (_Float16)ua.x; b0[1] = (_Float16)ua.y;
            b0[2] = (_Float16)ua.z; b0[3] = (_Float16)ua.w;
            b0[4] = (_Float16)ub.x; b0[5] = (_Float16)ub.y;
            b0[6] = (_Float16)ub.z; b0[7] = (_Float16)ub.w;
            b1[0] = (_Float16)uc.x; b1[1] = (_Float16)uc.y;
            b1[2] = (_Float16)uc.z; b1[3] = (_Float16)uc.w;
            b1[4] = (_Float16)ud.x; b1[5] = (_Float16)ud.y;
            b1[6] = (_Float16)ud.z; b1[7] = (_Float16)ud.w;
            acc0 = __builtin_amdgcn_mfma_f32_16x16x32_f16(wI0, b0, acc0, 0, 0, 0);
            acc1 = __builtin_amdgcn_mfma_f32_16x16x32_f16(wI1, b1, acc1, 0, 0, 0);
        }
        f32x4 acc = acc0 + acc1;

        // ---- C col 0 lanes publish partials (rows 4q..4q+3) ---------------
        if ((lane & 15) == 0) {
#pragma unroll
            for (int i = 0; i < 4; ++i)
                red[t & 1][4 * q + i][wv] = acc[i] - rs[i];
        }
        __syncthreads();                     // the ONE barrier per step

        // ---- wave wv reduces rows 2wv, 2wv+1 over 8 wave-partials ---------
        {
            const int row = 2 * wv + ((lane >> 3) & 1);
            float s = red[t & 1][row][lane & 7];
            s += __shfl_xor(s, 1, 64);
            s += __shfl_xor(s, 2, 64);
            s += __shfl_xor(s, 4, 64);       // lanes 0,8: row sums
            float s2 = __shfl_xor(s, 8, 64); // lane 0 <- row 2wv+1 sum
            if (lane == 0) {
                float x0 = tanhf(s), x1 = tanhf(s2);
                unsigned e0 = (unsigned)__half_as_ushort(__float2half_rn(x0 + 2.0f));
                unsigned e1 = (unsigned)__half_as_ushort(__float2half_rn(x1 + 2.0f));
                __hip_atomic_store((unsigned*)(Xh + (size_t)t * RES + 16 * g) + wv,
                                   e0 | (e1 << 16),
                                   __ATOMIC_RELAXED, __HIP_MEMORY_SCOPE_AGENT);
            }
        }
    }
}

// ---------------------------------------------------------------------------
// Readout: out[T,32] = decode(Xh) @ W_out. 2 t-rows/block.
// ---------------------------------------------------------------------------
__global__ __launch_bounds__(256)
void esn_out(const unsigned short* __restrict__ Xh,
             const float* __restrict__ Wout,
             float* __restrict__ out)
{
    __shared__ float xs[2 * RES];
    __shared__ float red[2][8][32];
    const int tid = threadIdx.x;
    const int t0  = blockIdx.x * 2;

    const uint4* s4 = (const uint4*)(Xh + (size_t)t0 * RES);
    for (int i = tid; i < 2 * RES / 8; i += 256) {
        uint4 v  = s4[i];
        float* d = &xs[8 * i];
        float2 f;
        f = __half22float2(*(__half2*)&v.x); d[0] = f.x - 2.f; d[1] = f.y - 2.f;
        f = __half22float2(*(__half2*)&v.y); d[2] = f.x - 2.f; d[3] = f.y - 2.f;
        f = __half22float2(*(__half2*)&v.z); d[4] = f.x - 2.f; d[5] = f.y - 2.f;
        f = __half22float2(*(__half2*)&v.w); d[6] = f.x - 2.f; d[7] = f.y - 2.f;
    }
    __syncthreads();

    const int o  = tid & 31;
    const int sg = tid >> 5;
    float acc0 = 0.f, acc1 = 0.f;
    const int rbeg = sg * 512;
    for (int rr = rbeg; rr < rbeg + 512; ++rr) {
        float wv = Wout[(size_t)rr * NOUT + o];
        acc0 += xs[rr] * wv;
        acc1 += xs[RES + rr] * wv;
    }
    red[0][sg][o] = acc0;
    red[1][sg][o] = acc1;
    __syncthreads();

    if (tid < 64) {
        const int h = tid >> 5, oo = tid & 31;
        float s = 0.f;
#pragma unroll
        for (int k = 0; k < 8; ++k) s += red[h][k][oo];
        out[(size_t)(t0 + h) * NOUT + oo] = s;
    }
}

// ---------------------------------------------------------------------------
extern "C" void kernel_launch(void* const* d_in, const int* in_sizes, int n_in,
                              void* d_out, int out_size, void* d_ws, size_t ws_size,
                              hipStream_t stream)
{
    const float* inputs = (const float*)d_in[0];   // [T, 64]
    const float* W_in   = (const float*)d_in[1];   // [RES, 64]
    const float* W      = (const float*)d_in[2];   // [RES, RES]
    const float* W_out  = (const float*)d_in[3];   // [RES, 32]
    float* out = (float*)d_out;                    // [T, 32]

    unsigned short* Xh = (unsigned short*)d_ws;    // [T][RES] fp16 encoded, 32 MiB

    // Replay-safe: zero history (0x0000 = "not written"), re-encode row 0.
    hipMemsetAsync(Xh, 0, (size_t)T_STEPS * RES * sizeof(unsigned short), stream);
    esn_init<<<dim3((RES + 255) / 256), dim3(256), 0, stream>>>(Xh);

    esn_recur<<<dim3(NWG), dim3(TPB), 0, stream>>>(inputs, W_in, W, Xh);
    esn_out<<<dim3(T_STEPS / 2), dim3(256), 0, stream>>>(Xh, W_out, out);
}

// Round 11
// 21985.268 us; speedup vs baseline: 1.0185x; 1.0185x over previous
//
#include <hip/hip_runtime.h>
#include <hip/hip_fp16.h>

#define T_STEPS 4096
#define RES     4096
#define NIN     64
#define NOUT    32
#define NWG     256
#define TPB     512   // 8 waves; wave wv owns cols [512wv,512wv+512) of all 16 rows
#define WS2     4104  // halfs per W row in LDS (4096 + 8 pad)

typedef unsigned long long ull;
typedef _Float16 half8 __attribute__((ext_vector_type(8)));
typedef float    f32x4 __attribute__((ext_vector_type(4)));

// all 4 encoded halfs nonzero? (published x+2 in (1,3): never 0x0000)
__device__ __forceinline__ bool ok4(ull q) {
    return ((unsigned short)q) && ((unsigned short)(q >> 16)) &&
           ((unsigned short)(q >> 32)) && ((unsigned short)(q >> 48));
}

__global__ void esn_init(unsigned short* __restrict__ Xh) {
    int i = blockIdx.x * 256 + threadIdx.x;
    if (i < RES) Xh[i] = 0x4000;               // half(2.0) == encoded x[0] = 0
}

// U = inputs @ W_in^T as fp16. Block: 16 t x 256 j. Grid (16, 256).
__global__ __launch_bounds__(256)
void esn_uproj(const float* __restrict__ inp, const float* __restrict__ Win,
               __half* __restrict__ Uh)
{
    __shared__ float us[16][NIN];
    const int tid = threadIdx.x;
    const int j   = blockIdx.x * 256 + tid;
    const int t0  = blockIdx.y * 16;
    ((float4*)us)[tid] = ((const float4*)(inp + (size_t)t0 * NIN))[tid];
    float wr[NIN];
    const float4* wp = (const float4*)(Win + (size_t)j * NIN);
#pragma unroll
    for (int k = 0; k < 16; ++k) {
        float4 v = wp[k];
        wr[4*k] = v.x; wr[4*k+1] = v.y; wr[4*k+2] = v.z; wr[4*k+3] = v.w;
    }
    __syncthreads();
#pragma unroll
    for (int tt = 0; tt < 16; ++tt) {
        float s = 0.f;
#pragma unroll
        for (int k = 0; k < NIN; ++k) s += wr[k] * us[tt][k];
        Uh[(size_t)(t0 + tt) * RES + j] = __float2half_rn(s);
    }
}

// ---------------------------------------------------------------------------
// Persistent recurrence, MFMA + LDS-rooted register fragments.
// 256 WGs x 512 thr; WG g owns rows 16g..16g+15; wave wv owns cols [512wv,+512).
//
// ROUND 2-10 POST-MORTEM, the residency war:
//   - compiler remats W values rooted in GLOBAL loads (r2-5, r9): 64 MB/step
//     restream. Remat only fires on provably-invariant global loads.
//   - physical-AGPR stash via asm clobbers (r10): clobbers don't RESERVE regs,
//     the allocator parks its own temps there between asms -> NaN.
//   - FIX: root the fragment loads in LDS. ds_read is NOT rematerializable
//     (LDS is mutable), so wA[16] (64 VGPRs) loaded pre-loop stays resident;
//     worst case the allocator spills to AGPRs (1-cycle accvgpr copies,
//     MFMA reads A from AGPR natively). Peak pressure ~170 < 256 cap.
//
// MFMA scheme (HW-validated end-to-end in r9, absmax == f32 rounds):
//   A frag lane(r=lane&15, q=lane>>4): W[16g+r][512wv+32c+8q+j], j=0..7.
//   B frag: x-slice duplicated across cols (only C col 0 consumed).
//   C layout col=lane&15, row=4q+reg. x encoded as x+2 (fp16, 0=unwritten);
//   the +2 is cancelled by initializing C with -2*rowsum(W) (ones-MFMA).
// U[t] = inputs@W_in^T precomputed (esn_uproj), added at the reduce.
// Sync: per-wave data-as-flag poll of exactly the consumed 1 KB slice (r8);
// ONE __syncthreads per step (parity-double-buffered red, proven safe).
// ---------------------------------------------------------------------------
__global__ __launch_bounds__(TPB, 1)
void esn_recur(const __half* __restrict__ Uh,
               const float* __restrict__ W,
               unsigned short* __restrict__ Xh)   // [T][RES] fp16 encoded
{
    __shared__ __align__(16) __half Wl[16 * WS2];  // 128.25 KiB fp16 W tile
    __shared__ __align__(16) __half xh[RES];       // 8 KiB wave-private slices
    __shared__ float red[2][16][9];                // padded partials, parity dbuf

    const int g    = blockIdx.x;
    const int tid  = threadIdx.x;
    const int wv   = tid >> 6;
    const int lane = tid & 63;
    const int q    = lane >> 4;      // k-subgroup 0..3 (8 k's each)
    const int r    = lane & 15;      // A row within the 16-row tile

    // ---- stage W -> LDS fp16 (once; coalesced 256 KB read per WG) ---------
    {
        const float4* Wg = (const float4*)(W + (size_t)g * 16 * RES);
        for (int idx = tid; idx < 16 * RES / 4; idx += TPB) {
            float4 v  = Wg[idx];
            int  row  = idx >> 10;
            int  c    = (idx & 1023) * 4;
            __half* d = &Wl[row * WS2 + c];
            d[0] = __float2half_rn(v.x);
            d[1] = __float2half_rn(v.y);
            d[2] = __float2half_rn(v.z);
            d[3] = __float2half_rn(v.w);
        }
    }
    __syncthreads();                               // W tile ready

    // ---- A-fragments: LDS -> registers ONCE (ds_read can't be rematted) ---
    half8 wA[16];
    {
        const half8* wrow = (const half8*)(Wl + r * WS2 + 512 * wv + 8 * q);
#pragma unroll
        for (int c = 0; c < 16; ++c) wA[c] = wrow[4 * c];
    }
    // ---- C-init = -2 * rowsum(W slice) via ones-MFMA (same layout path) ---
    f32x4 nrs;
    {
        half8 ones;
#pragma unroll
        for (int j = 0; j < 8; ++j) ones[j] = (_Float16)1.0f;
        f32x4 s0 = {0.f, 0.f, 0.f, 0.f}, s1 = {0.f, 0.f, 0.f, 0.f};
#pragma unroll
        for (int c = 0; c < 16; c += 2) {
            s0 = __builtin_amdgcn_mfma_f32_16x16x32_f16(wA[c],     ones, s0, 0, 0, 0);
            s1 = __builtin_amdgcn_mfma_f32_16x16x32_f16(wA[c + 1], ones, s1, 0, 0, 0);
        }
        nrs = (s0 + s1) * (-2.0f);
    }

    for (int t = 1; t < T_STEPS; ++t) {
        // ---- prefetch U[t] for my 2 rows (uniform 4 B; hides under poll) --
        const __half2 u2 = *(const __half2*)(Uh + (size_t)t * RES + 16 * g + 2 * wv);

        // ---- poll ONLY my wave's 16 B of x[t-1] (data-as-flag) ------------
        const ull* src = (const ull*)(Xh + (size_t)(t - 1) * RES) + 128 * wv + 2 * lane;
        ull q0 = 0, q1 = 0;
        int need = 3;
        do {
            if (need & 1) { q0 = __hip_atomic_load(src,     __ATOMIC_RELAXED, __HIP_MEMORY_SCOPE_AGENT); if (ok4(q0)) need &= ~1; }
            if (need & 2) { q1 = __hip_atomic_load(src + 1, __ATOMIC_RELAXED, __HIP_MEMORY_SCOPE_AGENT); if (ok4(q1)) need &= ~2; }
        } while (need);

        // ---- bounce raw encoded slice through LDS (wave-private) ----------
        uint4 sv;
        sv.x = (unsigned)q0; sv.y = (unsigned)(q0 >> 32);
        sv.z = (unsigned)q1; sv.w = (unsigned)(q1 >> 32);
        *(uint4*)(xh + 512 * wv + 8 * lane) = sv;
        asm volatile("s_waitcnt lgkmcnt(0)" ::: "memory");

        // ---- 16 MFMAs: C = -2*rowsum + A(W) * B(x^) -----------------------
        const half8* xb = (const half8*)(xh + 512 * wv);
        f32x4 acc0 = nrs;
        f32x4 acc1 = {0.f, 0.f, 0.f, 0.f};
#pragma unroll
        for (int c = 0; c < 16; c += 2) {
            acc0 = __builtin_amdgcn_mfma_f32_16x16x32_f16(wA[c],     xb[4 * c + q],       acc0, 0, 0, 0);
            acc1 = __builtin_amdgcn_mfma_f32_16x16x32_f16(wA[c + 1], xb[4 * (c + 1) + q], acc1, 0, 0, 0);
        }
        f32x4 acc = acc0 + acc1;

        // ---- C col 0 lanes publish partials (rows 4q..4q+3) ---------------
        if ((lane & 15) == 0) {
#pragma unroll
            for (int i = 0; i < 4; ++i)
                red[t & 1][4 * q + i][wv] = acc[i];
        }
        __syncthreads();                     // the ONE barrier per step

        // ---- wave wv reduces rows 2wv, 2wv+1; adds U[t]; publishes --------
        {
            const int row = 2 * wv + ((lane >> 3) & 1);
            float s = red[t & 1][row][lane & 7];
            s += __shfl_xor(s, 1, 64);
            s += __shfl_xor(s, 2, 64);
            s += __shfl_xor(s, 4, 64);       // lanes 0,8: row sums
            float s2 = __shfl_xor(s, 8, 64); // lane 0 <- row 2wv+1 sum
            if (lane == 0) {
                float2 uf = __half22float2(u2);
                float x0 = tanhf(s  + uf.x), x1 = tanhf(s2 + uf.y);
                unsigned e0 = (unsigned)__half_as_ushort(__float2half_rn(x0 + 2.0f));
                unsigned e1 = (unsigned)__half_as_ushort(__float2half_rn(x1 + 2.0f));
                __hip_atomic_store((unsigned*)(Xh + (size_t)t * RES + 16 * g) + wv,
                                   e0 | (e1 << 16),
                                   __ATOMIC_RELAXED, __HIP_MEMORY_SCOPE_AGENT);
            }
        }
    }
}

// ---------------------------------------------------------------------------
// Readout: out[T,32] = decode(Xh) @ W_out. 2 t-rows/block.
// ---------------------------------------------------------------------------
__global__ __launch_bounds__(256)
void esn_out(const unsigned short* __restrict__ Xh,
             const float* __restrict__ Wout,
             float* __restrict__ out)
{
    __shared__ float xs[2 * RES];
    __shared__ float red[2][8][32];
    const int tid = threadIdx.x;
    const int t0  = blockIdx.x * 2;

    const uint4* s4 = (const uint4*)(Xh + (size_t)t0 * RES);
    for (int i = tid; i < 2 * RES / 8; i += 256) {
        uint4 v  = s4[i];
        float* d = &xs[8 * i];
        float2 f;
        f = __half22float2(*(__half2*)&v.x); d[0] = f.x - 2.f; d[1] = f.y - 2.f;
        f = __half22float2(*(__half2*)&v.y); d[2] = f.x - 2.f; d[3] = f.y - 2.f;
        f = __half22float2(*(__half2*)&v.z); d[4] = f.x - 2.f; d[5] = f.y - 2.f;
        f = __half22float2(*(__half2*)&v.w); d[6] = f.x - 2.f; d[7] = f.y - 2.f;
    }
    __syncthreads();

    const int o  = tid & 31;
    const int sg = tid >> 5;
    float acc0 = 0.f, acc1 = 0.f;
    const int rbeg = sg * 512;
    for (int rr = rbeg; rr < rbeg + 512; ++rr) {
        float wv = Wout[(size_t)rr * NOUT + o];
        acc0 += xs[rr] * wv;
        acc1 += xs[RES + rr] * wv;
    }
    red[0][sg][o] = acc0;
    red[1][sg][o] = acc1;
    __syncthreads();

    if (tid < 64) {
        const int h = tid >> 5, oo = tid & 31;
        float s = 0.f;
#pragma unroll
        for (int k = 0; k < 8; ++k) s += red[h][k][oo];
        out[(size_t)(t0 + h) * NOUT + oo] = s;
    }
}

// ---------------------------------------------------------------------------
extern "C" void kernel_launch(void* const* d_in, const int* in_sizes, int n_in,
                              void* d_out, int out_size, void* d_ws, size_t ws_size,
                              hipStream_t stream)
{
    const float* inputs = (const float*)d_in[0];   // [T, 64]
    const float* W_in   = (const float*)d_in[1];   // [RES, 64]
    const float* W      = (const float*)d_in[2];   // [RES, RES]
    const float* W_out  = (const float*)d_in[3];   // [RES, 32]
    float* out = (float*)d_out;                    // [T, 32]

    unsigned short* Xh = (unsigned short*)d_ws;    // [T][RES] fp16 encoded, 32 MiB
    __half* Uh = (__half*)((char*)d_ws + (size_t)T_STEPS * RES * 2);  // 32 MiB

    // Replay-safe: zero history (0x0000 = "not written"), re-encode row 0.
    hipMemsetAsync(Xh, 0, (size_t)T_STEPS * RES * sizeof(unsigned short), stream);
    esn_init<<<dim3((RES + 255) / 256), dim3(256), 0, stream>>>(Xh);
    esn_uproj<<<dim3(RES / 256, T_STEPS / 16), dim3(256), 0, stream>>>(inputs, W_in, Uh);

    esn_recur<<<dim3(NWG), dim3(TPB), 0, stream>>>(Uh, W, Xh);
    esn_out<<<dim3(T_STEPS / 2), dim3(256), 0, stream>>>(Xh, W_out, out);
}

// Round 12
// 20906.750 us; speedup vs baseline: 1.0711x; 1.0516x over previous
//
#include <hip/hip_runtime.h>
#include <hip/hip_fp16.h>

#define T_STEPS 4096
#define RES     4096
#define NIN     64
#define NOUT    32
#define NWG     256
#define TPB     512   // 8 waves; wave wv owns cols [512wv,512wv+512) of all 16 rows
#define WS2     4104  // halfs per W row in LDS (4096 + 8 pad; 16B row-stride odd -> 2-way max)

typedef unsigned long long ull;
typedef _Float16 half8 __attribute__((ext_vector_type(8)));
typedef float    f32x4 __attribute__((ext_vector_type(4)));

// all 4 encoded halfs nonzero? (published x+2 in (1,3): never 0x0000)
__device__ __forceinline__ bool ok4(ull q) {
    return ((unsigned short)q) && ((unsigned short)(q >> 16)) &&
           ((unsigned short)(q >> 32)) && ((unsigned short)(q >> 48));
}

__global__ void esn_init(unsigned short* __restrict__ Xh) {
    int i = blockIdx.x * 256 + threadIdx.x;
    if (i < RES) Xh[i] = 0x4000;               // half(2.0) == encoded x[0] = 0
}

// U = inputs @ W_in^T as fp16. Block: 16 t x 256 j. Grid (16, 256).
__global__ __launch_bounds__(256)
void esn_uproj(const float* __restrict__ inp, const float* __restrict__ Win,
               __half* __restrict__ Uh)
{
    __shared__ float us[16][NIN];
    const int tid = threadIdx.x;
    const int j   = blockIdx.x * 256 + tid;
    const int t0  = blockIdx.y * 16;
    ((float4*)us)[tid] = ((const float4*)(inp + (size_t)t0 * NIN))[tid];
    float wr[NIN];
    const float4* wp = (const float4*)(Win + (size_t)j * NIN);
#pragma unroll
    for (int k = 0; k < 16; ++k) {
        float4 v = wp[k];
        wr[4*k] = v.x; wr[4*k+1] = v.y; wr[4*k+2] = v.z; wr[4*k+3] = v.w;
    }
    __syncthreads();
#pragma unroll
    for (int tt = 0; tt < 16; ++tt) {
        float s = 0.f;
#pragma unroll
        for (int k = 0; k < NIN; ++k) s += wr[k] * us[tt][k];
        Uh[(size_t)(t0 + tt) * RES + j] = __float2half_rn(s);
    }
}

// ---------------------------------------------------------------------------
// Persistent recurrence, MFMA + LDS W tile with LAUNDERED staging.
// 256 WGs x 512 thr; WG g owns rows 16g..16g+15; wave wv owns cols [512wv,+512).
//
// THE RESIDENCY WAR (r2-r11): the compiler restreams W from global/LLC at
// 64 MB/step whenever it can. r11's lesson: even with W staged to LDS, the
// loop's ds_reads were FORWARD-SUBSTITUTED back to the pure global->cvt chain
// that produced the stored values (store-to-load forwarding), and that chain
// was sunk into the t-loop -> r9-identical counters (FETCH 938 MB, 22 ms).
// FIX: launder each staged value through asm volatile before ds_write. The
// stored value becomes an asm output — no pure provenance — so the loop's
// ONLY legal source for the A-fragments is LDS. Allocator keeps them in
// 64 VGPRs (cap 256 via __launch_bounds__(512,2)) or re-reads LDS (~0.25us);
// both are fine, the restream is structurally dead.
//
// MFMA scheme (HW-validated r9/r11, absmax == f32 rounds):
//   A frag lane(r=lane&15, q=lane>>4): W[16g+r][512wv+32c+8q+j], j=0..7.
//   B frag: x-slice bounced through LDS (only C col 0 consumed).
//   C layout col=lane&15, row=4q+reg. x encoded x+2 (fp16, 0=unwritten);
//   +2 cancelled by C-init = -2*rowsum(W) (ones-MFMA).
// U[t] = inputs@W_in^T precomputed (esn_uproj), added at the reduce.
// Sync: per-wave data-as-flag poll of exactly the consumed 1 KB slice;
// ONE __syncthreads per step (parity-double-buffered red).
// ---------------------------------------------------------------------------
__global__ __launch_bounds__(TPB, 2)   // >=2 waves/SIMD => <=256 unified regs
void esn_recur(const __half* __restrict__ Uh,
               const float* __restrict__ W,
               unsigned short* __restrict__ Xh)   // [T][RES] fp16 encoded
{
    __shared__ __align__(16) __half Wl[16 * WS2];  // 128.25 KiB fp16 W tile
    __shared__ __align__(16) __half xh[RES];       // 8 KiB wave-private slices
    __shared__ float red[2][16][9];                // padded partials, parity dbuf

    const int g    = blockIdx.x;
    const int tid  = threadIdx.x;
    const int wv   = tid >> 6;
    const int lane = tid & 63;
    const int q    = lane >> 4;      // k-subgroup 0..3 (8 k's each)
    const int r    = lane & 15;      // A row within the 16-row tile

    // ---- stage W -> LDS fp16, LAUNDERED (once; coalesced 256 KB per WG) ---
    {
        const float4* Wg = (const float4*)(W + (size_t)g * 16 * RES);
        for (int idx = tid; idx < 16 * RES / 4; idx += TPB) {
            float4 v  = Wg[idx];
            int  row  = idx >> 10;
            int  c    = (idx & 1023) * 4;
            __half h0 = __float2half_rn(v.x), h1 = __float2half_rn(v.y);
            __half h2 = __float2half_rn(v.z), h3 = __float2half_rn(v.w);
            uint2 pk;
            pk.x = (unsigned)__half_as_ushort(h0) | ((unsigned)__half_as_ushort(h1) << 16);
            pk.y = (unsigned)__half_as_ushort(h2) | ((unsigned)__half_as_ushort(h3) << 16);
            // opaque def: stored value has no pure provenance -> no forwarding
            asm volatile("" : "+v"(pk.x), "+v"(pk.y));
            *(uint2*)&Wl[row * WS2 + c] = pk;
        }
    }
    __syncthreads();                               // W tile ready

    // ---- A-fragments: LDS -> registers ONCE (no remat source exists) ------
    half8 wA[16];
    {
        const half8* wrow = (const half8*)(Wl + r * WS2 + 512 * wv + 8 * q);
#pragma unroll
        for (int c = 0; c < 16; ++c) wA[c] = wrow[4 * c];
    }
    // ---- C-init = -2 * rowsum(W slice) via ones-MFMA (same layout path) ---
    f32x4 nrs;
    {
        half8 ones;
#pragma unroll
        for (int j = 0; j < 8; ++j) ones[j] = (_Float16)1.0f;
        f32x4 s0 = {0.f, 0.f, 0.f, 0.f}, s1 = {0.f, 0.f, 0.f, 0.f};
#pragma unroll
        for (int c = 0; c < 16; c += 2) {
            s0 = __builtin_amdgcn_mfma_f32_16x16x32_f16(wA[c],     ones, s0, 0, 0, 0);
            s1 = __builtin_amdgcn_mfma_f32_16x16x32_f16(wA[c + 1], ones, s1, 0, 0, 0);
        }
        nrs = (s0 + s1) * (-2.0f);
    }

    for (int t = 1; t < T_STEPS; ++t) {
        // ---- prefetch U[t] for my 2 rows (uniform 4 B; hides under poll) --
        const __half2 u2 = *(const __half2*)(Uh + (size_t)t * RES + 16 * g + 2 * wv);

        // ---- poll ONLY my wave's 16 B of x[t-1] (data-as-flag) ------------
        const ull* src = (const ull*)(Xh + (size_t)(t - 1) * RES) + 128 * wv + 2 * lane;
        ull q0 = 0, q1 = 0;
        int need = 3;
        do {
            if (need & 1) { q0 = __hip_atomic_load(src,     __ATOMIC_RELAXED, __HIP_MEMORY_SCOPE_AGENT); if (ok4(q0)) need &= ~1; }
            if (need & 2) { q1 = __hip_atomic_load(src + 1, __ATOMIC_RELAXED, __HIP_MEMORY_SCOPE_AGENT); if (ok4(q1)) need &= ~2; }
        } while (need);

        // ---- bounce raw encoded slice through LDS (wave-private) ----------
        uint4 sv;
        sv.x = (unsigned)q0; sv.y = (unsigned)(q0 >> 32);
        sv.z = (unsigned)q1; sv.w = (unsigned)(q1 >> 32);
        *(uint4*)(xh + 512 * wv + 8 * lane) = sv;
        asm volatile("s_waitcnt lgkmcnt(0)" ::: "memory");

        // ---- 16 MFMAs: C = -2*rowsum + A(W) * B(x^) -----------------------
        const half8* xb = (const half8*)(xh + 512 * wv);
        f32x4 acc0 = nrs;
        f32x4 acc1 = {0.f, 0.f, 0.f, 0.f};
#pragma unroll
        for (int c = 0; c < 16; c += 2) {
            acc0 = __builtin_amdgcn_mfma_f32_16x16x32_f16(wA[c],     xb[4 * c + q],       acc0, 0, 0, 0);
            acc1 = __builtin_amdgcn_mfma_f32_16x16x32_f16(wA[c + 1], xb[4 * (c + 1) + q], acc1, 0, 0, 0);
        }
        f32x4 acc = acc0 + acc1;

        // ---- C col 0 lanes publish partials (rows 4q..4q+3) ---------------
        if ((lane & 15) == 0) {
#pragma unroll
            for (int i = 0; i < 4; ++i)
                red[t & 1][4 * q + i][wv] = acc[i];
        }
        __syncthreads();                     // the ONE barrier per step

        // ---- wave wv reduces rows 2wv, 2wv+1; adds U[t]; publishes --------
        {
            const int row = 2 * wv + ((lane >> 3) & 1);
            float s = red[t & 1][row][lane & 7];
            s += __shfl_xor(s, 1, 64);
            s += __shfl_xor(s, 2, 64);
            s += __shfl_xor(s, 4, 64);       // lanes 0,8: row sums
            float s2 = __shfl_xor(s, 8, 64); // lane 0 <- row 2wv+1 sum
            if (lane == 0) {
                float2 uf = __half22float2(u2);
                float x0 = tanhf(s  + uf.x), x1 = tanhf(s2 + uf.y);
                unsigned e0 = (unsigned)__half_as_ushort(__float2half_rn(x0 + 2.0f));
                unsigned e1 = (unsigned)__half_as_ushort(__float2half_rn(x1 + 2.0f));
                __hip_atomic_store((unsigned*)(Xh + (size_t)t * RES + 16 * g) + wv,
                                   e0 | (e1 << 16),
                                   __ATOMIC_RELAXED, __HIP_MEMORY_SCOPE_AGENT);
            }
        }
    }
}

// ---------------------------------------------------------------------------
// Readout: out[T,32] = decode(Xh) @ W_out. 2 t-rows/block.
// ---------------------------------------------------------------------------
__global__ __launch_bounds__(256)
void esn_out(const unsigned short* __restrict__ Xh,
             const float* __restrict__ Wout,
             float* __restrict__ out)
{
    __shared__ float xs[2 * RES];
    __shared__ float red[2][8][32];
    const int tid = threadIdx.x;
    const int t0  = blockIdx.x * 2;

    const uint4* s4 = (const uint4*)(Xh + (size_t)t0 * RES);
    for (int i = tid; i < 2 * RES / 8; i += 256) {
        uint4 v  = s4[i];
        float* d = &xs[8 * i];
        float2 f;
        f = __half22float2(*(__half2*)&v.x); d[0] = f.x - 2.f; d[1] = f.y - 2.f;
        f = __half22float2(*(__half2*)&v.y); d[2] = f.x - 2.f; d[3] = f.y - 2.f;
        f = __half22float2(*(__half2*)&v.z); d[4] = f.x - 2.f; d[5] = f.y - 2.f;
        f = __half22float2(*(__half2*)&v.w); d[6] = f.x - 2.f; d[7] = f.y - 2.f;
    }
    __syncthreads();

    const int o  = tid & 31;
    const int sg = tid >> 5;
    float acc0 = 0.f, acc1 = 0.f;
    const int rbeg = sg * 512;
    for (int rr = rbeg; rr < rbeg + 512; ++rr) {
        float wv = Wout[(size_t)rr * NOUT + o];
        acc0 += xs[rr] * wv;
        acc1 += xs[RES + rr] * wv;
    }
    red[0][sg][o] = acc0;
    red[1][sg][o] = acc1;
    __syncthreads();

    if (tid < 64) {
        const int h = tid >> 5, oo = tid & 31;
        float s = 0.f;
#pragma unroll
        for (int k = 0; k < 8; ++k) s += red[h][k][oo];
        out[(size_t)(t0 + h) * NOUT + oo] = s;
    }
}

// ---------------------------------------------------------------------------
extern "C" void kernel_launch(void* const* d_in, const int* in_sizes, int n_in,
                              void* d_out, int out_size, void* d_ws, size_t ws_size,
                              hipStream_t stream)
{
    const float* inputs = (const float*)d_in[0];   // [T, 64]
    const float* W_in   = (const float*)d_in[1];   // [RES, 64]
    const float* W      = (const float*)d_in[2];   // [RES, RES]
    const float* W_out  = (const float*)d_in[3];   // [RES, 32]
    float* out = (float*)d_out;                    // [T, 32]

    unsigned short* Xh = (unsigned short*)d_ws;    // [T][RES] fp16 encoded, 32 MiB
    __half* Uh = (__half*)((char*)d_ws + (size_t)T_STEPS * RES * 2);  // 32 MiB

    // Replay-safe: zero history (0x0000 = "not written"), re-encode row 0.
    hipMemsetAsync(Xh, 0, (size_t)T_STEPS * RES * sizeof(unsigned short), stream);
    esn_init<<<dim3((RES + 255) / 256), dim3(256), 0, stream>>>(Xh);
    esn_uproj<<<dim3(RES / 256, T_STEPS / 16), dim3(256), 0, stream>>>(inputs, W_in, Uh);

    esn_recur<<<dim3(NWG), dim3(TPB), 0, stream>>>(Uh, W, Xh);
    esn_out<<<dim3(T_STEPS / 2), dim3(256), 0, stream>>>(Xh, W_out, out);
}